// Round 12
// baseline (3698.766 us; speedup 1.0000x reference)
//
#include <hip/hip_runtime.h>

// NewGRU: B=64, T=2048, D=256, U=256
// R12 = R11 (3217us scan) with barrier-shadow scheduling only (no numerics
// change):
//   1. barrier 2 moved into the NEXT step's preamble: vmcnt-wait + prefetch
//      issue + aU/aR ring reads + unpacks now execute BEFORE the sync that
//      closes the previous h-write (all of it wave-private ring work).
//   2. aO ring read + unpack moved BEFORE barrier 1 (after r-write).
// Race audit: preamble touches only the wave-private ring chunk; the moved
// barriers still separate h-write(t)/h-read(t+1) and r-write/r-read pairs.

#define TT 2048
#define DD 256

typedef __attribute__((ext_vector_type(8))) short short8;          // 8 x bf16 bits
typedef __attribute__((ext_vector_type(4))) unsigned short us4;    // 4 x bf16 bits
typedef __attribute__((ext_vector_type(2))) unsigned int uint2v;   // 8B store
typedef __attribute__((ext_vector_type(4))) float f32x4;

__device__ __forceinline__ unsigned short f2bf(float f) {          // RTN f32->bf16
  unsigned u = __float_as_uint(f);
  return (unsigned short)((u + 0x7FFFu + ((u >> 16) & 1u)) >> 16);
}
__device__ __forceinline__ float bf2f(unsigned short s) {
  return __uint_as_float(((unsigned)s) << 16);
}
// packed bf16 pair via the HW converter (RNE); plain VALU op (verified R10).
__device__ __forceinline__ unsigned cvtpk(float lo, float hi) {
  unsigned r;
  asm("v_cvt_pk_bf16_f32 %0, %1, %2" : "=v"(r) : "v"(lo), "v"(hi));
  return r;
}
// pre-scaled activations: input already multiplied by -log2e (u/r) or +2log2e (o)
__device__ __forceinline__ float sigp(float x) {   // sigmoid(orig), x=-1.4427*orig
  return __builtin_amdgcn_rcpf(1.f + __builtin_amdgcn_exp2f(x));
}
__device__ __forceinline__ float tanhp(float x) {  // tanh(orig), x=+2.8854*orig
  return __builtin_fmaf(-2.f, __builtin_amdgcn_rcpf(1.f + __builtin_amdgcn_exp2f(x)), 1.f);
}
__device__ __forceinline__ f32x4 mfma16(short8 a, short8 b, f32x4 c) {
  return __builtin_amdgcn_mfma_f32_16x16x32_bf16(a, b, c, 0, 0, 0);
}
__device__ __forceinline__ void load_lds16(const void* gp, void* lp) {
  __builtin_amdgcn_global_load_lds((__attribute__((address_space(1))) void*)(gp),
                                   (__attribute__((address_space(3))) void*)(lp),
                                   16, 0, 0);
}
// XOR swizzle used only by proj_kernel's x tile (verified R1).
__device__ __forceinline__ unsigned swz(unsigned row, unsigned byteInRow) {
  return row * 512u + (byteInRow ^ ((row & 7u) << 4));
}

#define SC_UR (-1.44269504f)
#define SC_O  ( 2.88539008f)

// ---------------------------------------------------------------------------
// proj_kernel: VERBATIM R11 (verified; weights/biases pre-scaled per gate).
// ---------------------------------------------------------------------------
__global__ __launch_bounds__(512) void proj_kernel(
    const float* __restrict__ x,
    const float* __restrict__ Wxu, const float* __restrict__ Wxr,
    const float* __restrict__ Wxo,
    const float* __restrict__ bu, const float* __restrict__ br,
    const float* __restrict__ bo,
    unsigned short* __restrict__ Ap)
{
  __shared__ alignas(16) unsigned short x_lds[16 * 256];

  const int tid = threadIdx.x;
  const int w = tid >> 6, l = tid & 63;
  const int q = l >> 4, b16 = l & 15;
  const int bblk = blockIdx.x & 3;
  const int tc = blockIdx.x >> 2;
  const int b0 = bblk * 16;

  short8 wx[6][8];
  f32x4 bbv[6];
#pragma unroll
  for (int n = 0; n < 6; ++n) {
    int ntg = w * 6 + n;
    const float* Wg = (ntg < 16) ? Wxu : (ntg < 32) ? Wxr : Wxo;
    const float* bg = (ntg < 16) ? bu : (ntg < 32) ? br : bo;
    const float sc = (ntg < 32) ? SC_UR : SC_O;
    int ct = ntg & 15;
    int col = ct * 16 + b16;
    int c0 = ct * 16 + q * 4;
    bbv[n] = (f32x4){bg[c0] * sc, bg[c0 + 1] * sc, bg[c0 + 2] * sc, bg[c0 + 3] * sc};
#pragma unroll
    for (int kt = 0; kt < 8; ++kt) {
      int k0 = kt * 32 + q * 8;
      short8 f;
#pragma unroll
      for (int j = 0; j < 8; ++j) f[j] = (short)f2bf(Wg[(k0 + j) * 256 + col] * sc);
      wx[n][kt] = f;
    }
  }

  for (int it = 0; it < 8; ++it) {
    const int t = tc * 8 + it;
    {
      int row = tid >> 5;
      int part = tid & 31;
      const float* src = x + (((size_t)(b0 + row) * TT + t) * DD) + part * 8;
      float4 f0 = *(const float4*)(src);
      float4 f1 = *(const float4*)(src + 4);
      us4 s0 = { f2bf(f0.x), f2bf(f0.y), f2bf(f0.z), f2bf(f0.w) };
      us4 s1 = { f2bf(f1.x), f2bf(f1.y), f2bf(f1.z), f2bf(f1.w) };
      unsigned base = swz((unsigned)row, (unsigned)(part * 16));
      *(us4*)((char*)x_lds + base) = s0;
      *(us4*)((char*)x_lds + base + 8) = s1;
    }
    __syncthreads();

    f32x4 acc[6];
#pragma unroll
    for (int n = 0; n < 6; ++n) acc[n] = bbv[n];
#pragma unroll
    for (int kt = 0; kt < 8; ++kt) {
      short8 xa = *(const short8*)((const char*)x_lds + swz(b16, kt * 64 + q * 16));
#pragma unroll
      for (int n = 0; n < 6; ++n) acc[n] = mfma16(wx[n][kt], xa, acc[n]);
    }
    __syncthreads();

#pragma unroll
    for (int n = 0; n < 6; ++n) {
      int ntg = w * 6 + n;
      int g = ntg >> 4, ct = ntg & 15;
      us4 st = { f2bf(acc[n][0]), f2bf(acc[n][1]), f2bf(acc[n][2]), f2bf(acc[n][3]) };
      size_t base = (((size_t)t * 3 + g) * 4 + bblk) * 4096
                    + (ct >> 1) * 512 + l * 8 + (ct & 1) * 4;
      *(us4*)(Ap + base) = st;
    }
  }
}

// ---------------------------------------------------------------------------
// scan_kernel: R11 structure; barriers repositioned into work shadows.
// ---------------------------------------------------------------------------
#define RING_SLOT 24576
#define HOFF 98304
#define ROFF 107008

__global__ __launch_bounds__(512, 2) void scan_kernel(
    const float* __restrict__ Whu, const float* __restrict__ Whr,
    const float* __restrict__ Wro,
    const unsigned short* __restrict__ Ap,
    float* __restrict__ out)
{
  __shared__ alignas(16) char lds8[115712];

  const int tid = threadIdx.x;
  const int w = tid >> 6, l = tid & 63;
  const int q = l >> 4, b16 = l & 15;
  const int bblk = blockIdx.x;
  const int cw = w * 32;

  short8 wbu[2][8], wbr[2][8], wbo[2][8];
#pragma unroll
  for (int n = 0; n < 2; ++n) {
    const int col = cw + n * 16 + b16;
#pragma unroll
    for (int kt = 0; kt < 8; ++kt) {
      const int k0 = kt * 32 + q * 8;
      short8 fu, fr, fo;
#pragma unroll
      for (int j = 0; j < 8; ++j) {
        fu[j] = (short)f2bf(Whu[(k0 + j) * 256 + col] * SC_UR);
        fr[j] = (short)f2bf(Whr[(k0 + j) * 256 + col] * SC_UR);
        fo[j] = (short)f2bf(Wro[(k0 + j) * 256 + col] * SC_O);
      }
      wbu[n][kt] = fu; wbr[n][kt] = fr; wbo[n][kt] = fo;
    }
  }

  const unsigned rowb = (unsigned)(b16 * 544);
  const char* hrd = lds8 + HOFF + rowb + q * 16;           // + kt*64 (imm)
  const char* rrd = lds8 + ROFF + rowb + q * 16;
  char* hwr0 = lds8 + HOFF + rowb + (cw + q * 4) * 2;      // 8B; second at +32
  char* rwr0 = lds8 + ROFF + rowb + (cw + q * 4) * 2;
  const char* ringr = lds8 + w * 1024 + l * 16;            // + slot*24576 + g*8192

  const unsigned short* apl = Ap + (size_t)bblk * 4096 + w * 512 + l * 8;

  for (int i = tid; i < 8704 / 4; i += 512) *(int*)(lds8 + HOFF + i * 4) = 0;

  float hm0 = 0, hm1 = 0, hm2 = 0, hm3 = 0, hm4 = 0, hm5 = 0, hm6 = 0, hm7 = 0;

#pragma unroll
  for (int t0 = 0; t0 < 3; ++t0) {
    const unsigned short* s = apl + (size_t)t0 * 49152u;
    char* d = lds8 + (t0 & 3) * RING_SLOT + w * 1024;
    load_lds16(s,         d);
    load_lds16(s + 16384, d + 8192);
    load_lds16(s + 32768, d + 16384);
  }
  __syncthreads();   // h zeros visible; also serves as step-0's preamble sync

#define STEP_BODY(T, SLOT, PSLOT)                                                \
  {                                                                              \
    /* ---- preamble (wave-private ring work; overlaps other waves' tail) ---- */\
    asm volatile("s_waitcnt vmcnt(6)" ::: "memory");                             \
    { /* prefetch step T+3 (clamped; duplicate loads write identical bytes) */   \
      int tp = (T) + 3; if (tp > TT - 1) tp = TT - 1;                            \
      const unsigned short* s = apl + (size_t)tp * 49152u;                       \
      char* d = lds8 + (PSLOT) * RING_SLOT + w * 1024;                           \
      load_lds16(s,         d);                                                  \
      load_lds16(s + 16384, d + 8192);                                           \
      load_lds16(s + 32768, d + 16384);                                          \
    }                                                                            \
    const char* rp = ringr + (SLOT) * RING_SLOT;                                 \
    short8 aU = *(const short8*)(rp);                                            \
    short8 aR = *(const short8*)(rp + 8192);                                     \
    f32x4 accu0 = (f32x4){bf2f((unsigned short)aU[0]), bf2f((unsigned short)aU[1]), \
                          bf2f((unsigned short)aU[2]), bf2f((unsigned short)aU[3])}; \
    f32x4 accu1 = (f32x4){bf2f((unsigned short)aU[4]), bf2f((unsigned short)aU[5]), \
                          bf2f((unsigned short)aU[6]), bf2f((unsigned short)aU[7])}; \
    f32x4 accr0 = (f32x4){bf2f((unsigned short)aR[0]), bf2f((unsigned short)aR[1]), \
                          bf2f((unsigned short)aR[2]), bf2f((unsigned short)aR[3])}; \
    f32x4 accr1 = (f32x4){bf2f((unsigned short)aR[4]), bf2f((unsigned short)aR[5]), \
                          bf2f((unsigned short)aR[6]), bf2f((unsigned short)aR[7])}; \
    /* barrier A: closes the PREVIOUS step's h-write (each wave already     */   \
    /* drained its own LDS ops via trailing lgkmcnt(0))                     */   \
    __builtin_amdgcn_s_barrier();                                                \
    asm volatile("" ::: "memory");                                               \
    _Pragma("unroll")                                                            \
    for (int kt = 0; kt < 8; ++kt) {                                             \
      short8 ha = *(const short8*)(hrd + kt * 64);                               \
      accr0 = mfma16(wbr[0][kt], ha, accr0);                                     \
      accr1 = mfma16(wbr[1][kt], ha, accr1);                                     \
      accu0 = mfma16(wbu[0][kt], ha, accu0);                                     \
      accu1 = mfma16(wbu[1][kt], ha, accu1);                                     \
    }                                                                            \
    { /* r = sigp, cvt_pk pack, write */                                         \
      float ra0 = sigp(accr0[0]), ra1 = sigp(accr0[1]);                          \
      float ra2 = sigp(accr0[2]), ra3 = sigp(accr0[3]);                          \
      float rb0 = sigp(accr1[0]), rb1 = sigp(accr1[1]);                          \
      float rb2 = sigp(accr1[2]), rb3 = sigp(accr1[3]);                          \
      *(uint2v*)(rwr0)      = (uint2v){cvtpk(ra0, ra1), cvtpk(ra2, ra3)};        \
      *(uint2v*)(rwr0 + 32) = (uint2v){cvtpk(rb0, rb1), cvtpk(rb2, rb3)};        \
    }                                                                            \
    /* aO read + unpack BEFORE barrier B (wave-private ring slot) */             \
    short8 aO = *(const short8*)(rp + 16384);                                    \
    f32x4 acco0 = (f32x4){bf2f((unsigned short)aO[0]), bf2f((unsigned short)aO[1]), \
                          bf2f((unsigned short)aO[2]), bf2f((unsigned short)aO[3])}; \
    f32x4 acco1 = (f32x4){bf2f((unsigned short)aO[4]), bf2f((unsigned short)aO[5]), \
                          bf2f((unsigned short)aO[6]), bf2f((unsigned short)aO[7])}; \
    asm volatile("s_waitcnt lgkmcnt(0)" ::: "memory");                           \
    __builtin_amdgcn_s_barrier();    /* barrier B: r exchange */                 \
    asm volatile("" ::: "memory");                                               \
    _Pragma("unroll")                                                            \
    for (int kt = 0; kt < 8; ++kt) {                                             \
      short8 ra = *(const short8*)(rrd + kt * 64);                               \
      acco0 = mfma16(wbo[0][kt], ra, acco0);                                     \
      acco1 = mfma16(wbo[1][kt], ra, acco1);                                     \
    }                                                                            \
    {                                                                            \
      float u0 = sigp(accu0[0]), u1 = sigp(accu0[1]);                            \
      float u2 = sigp(accu0[2]), u3 = sigp(accu0[3]);                            \
      float u4 = sigp(accu1[0]), u5 = sigp(accu1[1]);                            \
      float u6 = sigp(accu1[2]), u7 = sigp(accu1[3]);                            \
      hm0 += u0 * (tanhp(acco0[0]) - hm0);                                       \
      hm1 += u1 * (tanhp(acco0[1]) - hm1);                                       \
      hm2 += u2 * (tanhp(acco0[2]) - hm2);                                       \
      hm3 += u3 * (tanhp(acco0[3]) - hm3);                                       \
      hm4 += u4 * (tanhp(acco1[0]) - hm4);                                       \
      hm5 += u5 * (tanhp(acco1[1]) - hm5);                                       \
      hm6 += u6 * (tanhp(acco1[2]) - hm6);                                       \
      hm7 += u7 * (tanhp(acco1[3]) - hm7);                                       \
      *(uint2v*)(hwr0)      = (uint2v){cvtpk(hm0, hm1), cvtpk(hm2, hm3)};        \
      *(uint2v*)(hwr0 + 32) = (uint2v){cvtpk(hm4, hm5), cvtpk(hm6, hm7)};        \
    }                                                                            \
    /* drain own LDS ops; barrier A of the NEXT step completes the exchange */   \
    asm volatile("s_waitcnt lgkmcnt(0)" ::: "memory");                           \
  }

  for (int t = 0; t < TT; t += 4) {
    STEP_BODY(t,     0, 3)
    STEP_BODY(t + 1, 1, 0)
    STEP_BODY(t + 2, 2, 1)
    STEP_BODY(t + 3, 3, 2)
  }
#undef STEP_BODY

  const int orow = bblk * 16 + b16;
  const int c0 = cw + q * 4;
  *(f32x4*)(&out[orow * 256 + c0])      = (f32x4){hm0, hm1, hm2, hm3};
  *(f32x4*)(&out[orow * 256 + c0 + 16]) = (f32x4){hm4, hm5, hm6, hm7};
}

__global__ void ws_signal_kernel(float* out, float v) {
  out[blockIdx.x * 256 + threadIdx.x] = v;
}

extern "C" void kernel_launch(void* const* d_in, const int* in_sizes, int n_in,
                              void* d_out, int out_size, void* d_ws, size_t ws_size,
                              hipStream_t stream) {
  const float* x   = (const float*)d_in[0];
  const float* Wxu = (const float*)d_in[1];
  const float* Whu = (const float*)d_in[2];
  const float* bu  = (const float*)d_in[3];
  const float* Wxr = (const float*)d_in[4];
  const float* Whr = (const float*)d_in[5];
  const float* br  = (const float*)d_in[6];
  const float* Wxo = (const float*)d_in[7];
  const float* Wro = (const float*)d_in[8];
  const float* bo  = (const float*)d_in[9];
  float* out = (float*)d_out;

  const size_t needed = (size_t)TT * 3 * 4 * 4096 * 2;  // 192 MiB bf16 A'
  if (ws_size < needed) {
    ws_signal_kernel<<<64, 256, 0, stream>>>(out, (float)(ws_size >> 20));
    return;
  }
  unsigned short* Ap = (unsigned short*)d_ws;
  proj_kernel<<<1024, 512, 0, stream>>>(x, Wxu, Wxr, Wxo, bu, br, bo, Ap);
  scan_kernel<<<4, 512, 0, stream>>>(Whu, Whr, Wro, Ap, out);
}

// Round 13
// 3544.411 us; speedup vs baseline: 1.0435x; 1.0435x over previous
//
#include <hip/hip_runtime.h>

// NewGRU: B=64, T=2048, D=256, U=256
// R13 = VERBATIM R11 (best verified: scan 3217us, total 3567us).
// R12's barrier reposition regressed (+4.5%) and is reverted: with 2-wave/SIMD
// lockstep phases, preamble work placed BEFORE the barrier serializes into the
// inter-wave critical path; R11's post-barrier placement rides the slack.
//   - 4 CUs x 8 waves x 32 cols; 544B-stride conflict-free h/r tiles
//   - A' via 4-slot global_load_lds ring, counted vmcnt(6), never drained
//   - weights bf16 register-resident, pre-scaled by -log2e (u,r) / +2log2e (o)
//   - activations: rcp(1+exp2(x)) forms; cvt_pk_bf16 packing

#define TT 2048
#define DD 256

typedef __attribute__((ext_vector_type(8))) short short8;          // 8 x bf16 bits
typedef __attribute__((ext_vector_type(4))) unsigned short us4;    // 4 x bf16 bits
typedef __attribute__((ext_vector_type(2))) unsigned int uint2v;   // 8B store
typedef __attribute__((ext_vector_type(4))) float f32x4;

__device__ __forceinline__ unsigned short f2bf(float f) {          // RTN f32->bf16
  unsigned u = __float_as_uint(f);
  return (unsigned short)((u + 0x7FFFu + ((u >> 16) & 1u)) >> 16);
}
__device__ __forceinline__ float bf2f(unsigned short s) {
  return __uint_as_float(((unsigned)s) << 16);
}
// packed bf16 pair via the HW converter (RNE); plain VALU op (verified R10).
__device__ __forceinline__ unsigned cvtpk(float lo, float hi) {
  unsigned r;
  asm("v_cvt_pk_bf16_f32 %0, %1, %2" : "=v"(r) : "v"(lo), "v"(hi));
  return r;
}
// pre-scaled activations: input already multiplied by -log2e (u/r) or +2log2e (o)
__device__ __forceinline__ float sigp(float x) {   // sigmoid(orig), x=-1.4427*orig
  return __builtin_amdgcn_rcpf(1.f + __builtin_amdgcn_exp2f(x));
}
__device__ __forceinline__ float tanhp(float x) {  // tanh(orig), x=+2.8854*orig
  return __builtin_fmaf(-2.f, __builtin_amdgcn_rcpf(1.f + __builtin_amdgcn_exp2f(x)), 1.f);
}
__device__ __forceinline__ f32x4 mfma16(short8 a, short8 b, f32x4 c) {
  return __builtin_amdgcn_mfma_f32_16x16x32_bf16(a, b, c, 0, 0, 0);
}
__device__ __forceinline__ void load_lds16(const void* gp, void* lp) {
  __builtin_amdgcn_global_load_lds((__attribute__((address_space(1))) void*)(gp),
                                   (__attribute__((address_space(3))) void*)(lp),
                                   16, 0, 0);
}
// XOR swizzle used only by proj_kernel's x tile (verified R1).
__device__ __forceinline__ unsigned swz(unsigned row, unsigned byteInRow) {
  return row * 512u + (byteInRow ^ ((row & 7u) << 4));
}

#define SC_UR (-1.44269504f)
#define SC_O  ( 2.88539008f)

// ---------------------------------------------------------------------------
// proj_kernel: R4 structure; weight/bias scaled per gate (u,r: -1.4427; o: +2.8854).
// ---------------------------------------------------------------------------
__global__ __launch_bounds__(512) void proj_kernel(
    const float* __restrict__ x,
    const float* __restrict__ Wxu, const float* __restrict__ Wxr,
    const float* __restrict__ Wxo,
    const float* __restrict__ bu, const float* __restrict__ br,
    const float* __restrict__ bo,
    unsigned short* __restrict__ Ap)
{
  __shared__ alignas(16) unsigned short x_lds[16 * 256];

  const int tid = threadIdx.x;
  const int w = tid >> 6, l = tid & 63;
  const int q = l >> 4, b16 = l & 15;
  const int bblk = blockIdx.x & 3;
  const int tc = blockIdx.x >> 2;
  const int b0 = bblk * 16;

  short8 wx[6][8];
  f32x4 bbv[6];
#pragma unroll
  for (int n = 0; n < 6; ++n) {
    int ntg = w * 6 + n;
    const float* Wg = (ntg < 16) ? Wxu : (ntg < 32) ? Wxr : Wxo;
    const float* bg = (ntg < 16) ? bu : (ntg < 32) ? br : bo;
    const float sc = (ntg < 32) ? SC_UR : SC_O;
    int ct = ntg & 15;
    int col = ct * 16 + b16;
    int c0 = ct * 16 + q * 4;
    bbv[n] = (f32x4){bg[c0] * sc, bg[c0 + 1] * sc, bg[c0 + 2] * sc, bg[c0 + 3] * sc};
#pragma unroll
    for (int kt = 0; kt < 8; ++kt) {
      int k0 = kt * 32 + q * 8;
      short8 f;
#pragma unroll
      for (int j = 0; j < 8; ++j) f[j] = (short)f2bf(Wg[(k0 + j) * 256 + col] * sc);
      wx[n][kt] = f;
    }
  }

  for (int it = 0; it < 8; ++it) {
    const int t = tc * 8 + it;
    {
      int row = tid >> 5;
      int part = tid & 31;
      const float* src = x + (((size_t)(b0 + row) * TT + t) * DD) + part * 8;
      float4 f0 = *(const float4*)(src);
      float4 f1 = *(const float4*)(src + 4);
      us4 s0 = { f2bf(f0.x), f2bf(f0.y), f2bf(f0.z), f2bf(f0.w) };
      us4 s1 = { f2bf(f1.x), f2bf(f1.y), f2bf(f1.z), f2bf(f1.w) };
      unsigned base = swz((unsigned)row, (unsigned)(part * 16));
      *(us4*)((char*)x_lds + base) = s0;
      *(us4*)((char*)x_lds + base + 8) = s1;
    }
    __syncthreads();

    f32x4 acc[6];
#pragma unroll
    for (int n = 0; n < 6; ++n) acc[n] = bbv[n];
#pragma unroll
    for (int kt = 0; kt < 8; ++kt) {
      short8 xa = *(const short8*)((const char*)x_lds + swz(b16, kt * 64 + q * 16));
#pragma unroll
      for (int n = 0; n < 6; ++n) acc[n] = mfma16(wx[n][kt], xa, acc[n]);
    }
    __syncthreads();

#pragma unroll
    for (int n = 0; n < 6; ++n) {
      int ntg = w * 6 + n;
      int g = ntg >> 4, ct = ntg & 15;
      us4 st = { f2bf(acc[n][0]), f2bf(acc[n][1]), f2bf(acc[n][2]), f2bf(acc[n][3]) };
      size_t base = (((size_t)t * 3 + g) * 4 + bblk) * 4096
                    + (ct >> 1) * 512 + l * 8 + (ct & 1) * 4;
      *(us4*)(Ap + base) = st;
    }
  }
}

// ---------------------------------------------------------------------------
// scan_kernel: R10 structure; scaled weights; pre-scaled activations; 4-deep
// unroll with compile-time ring slots.
// ---------------------------------------------------------------------------
#define RING_SLOT 24576
#define HOFF 98304
#define ROFF 107008

__global__ __launch_bounds__(512, 2) void scan_kernel(
    const float* __restrict__ Whu, const float* __restrict__ Whr,
    const float* __restrict__ Wro,
    const unsigned short* __restrict__ Ap,
    float* __restrict__ out)
{
  __shared__ alignas(16) char lds8[115712];

  const int tid = threadIdx.x;
  const int w = tid >> 6, l = tid & 63;
  const int q = l >> 4, b16 = l & 15;
  const int bblk = blockIdx.x;
  const int cw = w * 32;

  short8 wbu[2][8], wbr[2][8], wbo[2][8];
#pragma unroll
  for (int n = 0; n < 2; ++n) {
    const int col = cw + n * 16 + b16;
#pragma unroll
    for (int kt = 0; kt < 8; ++kt) {
      const int k0 = kt * 32 + q * 8;
      short8 fu, fr, fo;
#pragma unroll
      for (int j = 0; j < 8; ++j) {
        fu[j] = (short)f2bf(Whu[(k0 + j) * 256 + col] * SC_UR);
        fr[j] = (short)f2bf(Whr[(k0 + j) * 256 + col] * SC_UR);
        fo[j] = (short)f2bf(Wro[(k0 + j) * 256 + col] * SC_O);
      }
      wbu[n][kt] = fu; wbr[n][kt] = fr; wbo[n][kt] = fo;
    }
  }

  const unsigned rowb = (unsigned)(b16 * 544);
  const char* hrd = lds8 + HOFF + rowb + q * 16;           // + kt*64 (imm)
  const char* rrd = lds8 + ROFF + rowb + q * 16;
  char* hwr0 = lds8 + HOFF + rowb + (cw + q * 4) * 2;      // 8B; second at +32
  char* rwr0 = lds8 + ROFF + rowb + (cw + q * 4) * 2;
  const char* ringr = lds8 + w * 1024 + l * 16;            // + slot*24576 + g*8192

  const unsigned short* apl = Ap + (size_t)bblk * 4096 + w * 512 + l * 8;

  for (int i = tid; i < 8704 / 4; i += 512) *(int*)(lds8 + HOFF + i * 4) = 0;

  float hm0 = 0, hm1 = 0, hm2 = 0, hm3 = 0, hm4 = 0, hm5 = 0, hm6 = 0, hm7 = 0;

#pragma unroll
  for (int t0 = 0; t0 < 3; ++t0) {
    const unsigned short* s = apl + (size_t)t0 * 49152u;
    char* d = lds8 + (t0 & 3) * RING_SLOT + w * 1024;
    load_lds16(s,         d);
    load_lds16(s + 16384, d + 8192);
    load_lds16(s + 32768, d + 16384);
  }
  __syncthreads();

#define STEP_BODY(T, SLOT, PSLOT)                                                \
  {                                                                              \
    asm volatile("s_waitcnt vmcnt(6)" ::: "memory");                             \
    { /* prefetch step T+3 (clamped; duplicate loads write identical bytes) */   \
      int tp = (T) + 3; if (tp > TT - 1) tp = TT - 1;                            \
      const unsigned short* s = apl + (size_t)tp * 49152u;                       \
      char* d = lds8 + (PSLOT) * RING_SLOT + w * 1024;                           \
      load_lds16(s,         d);                                                  \
      load_lds16(s + 16384, d + 8192);                                           \
      load_lds16(s + 32768, d + 16384);                                          \
    }                                                                            \
    const char* rp = ringr + (SLOT) * RING_SLOT;                                 \
    short8 aU = *(const short8*)(rp);                                            \
    short8 aR = *(const short8*)(rp + 8192);                                     \
    f32x4 accu0 = (f32x4){bf2f((unsigned short)aU[0]), bf2f((unsigned short)aU[1]), \
                          bf2f((unsigned short)aU[2]), bf2f((unsigned short)aU[3])}; \
    f32x4 accu1 = (f32x4){bf2f((unsigned short)aU[4]), bf2f((unsigned short)aU[5]), \
                          bf2f((unsigned short)aU[6]), bf2f((unsigned short)aU[7])}; \
    f32x4 accr0 = (f32x4){bf2f((unsigned short)aR[0]), bf2f((unsigned short)aR[1]), \
                          bf2f((unsigned short)aR[2]), bf2f((unsigned short)aR[3])}; \
    f32x4 accr1 = (f32x4){bf2f((unsigned short)aR[4]), bf2f((unsigned short)aR[5]), \
                          bf2f((unsigned short)aR[6]), bf2f((unsigned short)aR[7])}; \
    _Pragma("unroll")                                                            \
    for (int kt = 0; kt < 8; ++kt) {                                             \
      short8 ha = *(const short8*)(hrd + kt * 64);                               \
      accr0 = mfma16(wbr[0][kt], ha, accr0);                                     \
      accr1 = mfma16(wbr[1][kt], ha, accr1);                                     \
      accu0 = mfma16(wbu[0][kt], ha, accu0);                                     \
      accu1 = mfma16(wbu[1][kt], ha, accu1);                                     \
    }                                                                            \
    { /* r = sigp (pre-scaled), cvt_pk pack, write */                            \
      float ra0 = sigp(accr0[0]), ra1 = sigp(accr0[1]);                          \
      float ra2 = sigp(accr0[2]), ra3 = sigp(accr0[3]);                          \
      float rb0 = sigp(accr1[0]), rb1 = sigp(accr1[1]);                          \
      float rb2 = sigp(accr1[2]), rb3 = sigp(accr1[3]);                          \
      *(uint2v*)(rwr0)      = (uint2v){cvtpk(ra0, ra1), cvtpk(ra2, ra3)};        \
      *(uint2v*)(rwr0 + 32) = (uint2v){cvtpk(rb0, rb1), cvtpk(rb2, rb3)};        \
    }                                                                            \
    asm volatile("s_waitcnt lgkmcnt(0)" ::: "memory");                           \
    __builtin_amdgcn_s_barrier();                                                \
    asm volatile("" ::: "memory");                                               \
    /* ---- phase 2: o-gate ring read here (slot live; own slice) ---- */        \
    short8 aO = *(const short8*)(rp + 16384);                                    \
    f32x4 acco0 = (f32x4){bf2f((unsigned short)aO[0]), bf2f((unsigned short)aO[1]), \
                          bf2f((unsigned short)aO[2]), bf2f((unsigned short)aO[3])}; \
    f32x4 acco1 = (f32x4){bf2f((unsigned short)aO[4]), bf2f((unsigned short)aO[5]), \
                          bf2f((unsigned short)aO[6]), bf2f((unsigned short)aO[7])}; \
    _Pragma("unroll")                                                            \
    for (int kt = 0; kt < 8; ++kt) {                                             \
      short8 ra = *(const short8*)(rrd + kt * 64);                               \
      acco0 = mfma16(wbo[0][kt], ra, acco0);                                     \
      acco1 = mfma16(wbo[1][kt], ra, acco1);                                     \
    }                                                                            \
    {                                                                            \
      float u0 = sigp(accu0[0]), u1 = sigp(accu0[1]);                            \
      float u2 = sigp(accu0[2]), u3 = sigp(accu0[3]);                            \
      float u4 = sigp(accu1[0]), u5 = sigp(accu1[1]);                            \
      float u6 = sigp(accu1[2]), u7 = sigp(accu1[3]);                            \
      hm0 += u0 * (tanhp(acco0[0]) - hm0);                                       \
      hm1 += u1 * (tanhp(acco0[1]) - hm1);                                       \
      hm2 += u2 * (tanhp(acco0[2]) - hm2);                                       \
      hm3 += u3 * (tanhp(acco0[3]) - hm3);                                       \
      hm4 += u4 * (tanhp(acco1[0]) - hm4);                                       \
      hm5 += u5 * (tanhp(acco1[1]) - hm5);                                       \
      hm6 += u6 * (tanhp(acco1[2]) - hm6);                                       \
      hm7 += u7 * (tanhp(acco1[3]) - hm7);                                       \
      *(uint2v*)(hwr0)      = (uint2v){cvtpk(hm0, hm1), cvtpk(hm2, hm3)};        \
      *(uint2v*)(hwr0 + 32) = (uint2v){cvtpk(hm4, hm5), cvtpk(hm6, hm7)};        \
    }                                                                            \
    asm volatile("s_waitcnt lgkmcnt(0)" ::: "memory");                           \
    __builtin_amdgcn_s_barrier();                                                \
    asm volatile("" ::: "memory");                                               \
  }

  for (int t = 0; t < TT; t += 4) {
    STEP_BODY(t,     0, 3)
    STEP_BODY(t + 1, 1, 0)
    STEP_BODY(t + 2, 2, 1)
    STEP_BODY(t + 3, 3, 2)
  }
#undef STEP_BODY

  const int orow = bblk * 16 + b16;
  const int c0 = cw + q * 4;
  *(f32x4*)(&out[orow * 256 + c0])      = (f32x4){hm0, hm1, hm2, hm3};
  *(f32x4*)(&out[orow * 256 + c0 + 16]) = (f32x4){hm4, hm5, hm6, hm7};
}

__global__ void ws_signal_kernel(float* out, float v) {
  out[blockIdx.x * 256 + threadIdx.x] = v;
}

extern "C" void kernel_launch(void* const* d_in, const int* in_sizes, int n_in,
                              void* d_out, int out_size, void* d_ws, size_t ws_size,
                              hipStream_t stream) {
  const float* x   = (const float*)d_in[0];
  const float* Wxu = (const float*)d_in[1];
  const float* Whu = (const float*)d_in[2];
  const float* bu  = (const float*)d_in[3];
  const float* Wxr = (const float*)d_in[4];
  const float* Whr = (const float*)d_in[5];
  const float* br  = (const float*)d_in[6];
  const float* Wxo = (const float*)d_in[7];
  const float* Wro = (const float*)d_in[8];
  const float* bo  = (const float*)d_in[9];
  float* out = (float*)d_out;

  const size_t needed = (size_t)TT * 3 * 4 * 4096 * 2;  // 192 MiB bf16 A'
  if (ws_size < needed) {
    ws_signal_kernel<<<64, 256, 0, stream>>>(out, (float)(ws_size >> 20));
    return;
  }
  unsigned short* Ap = (unsigned short*)d_ws;
  proj_kernel<<<1024, 512, 0, stream>>>(x, Wxu, Wxr, Wxo, bu, br, bo, Ap);
  scan_kernel<<<4, 512, 0, stream>>>(Whu, Whr, Wro, Ap, out);
}